// Round 10
// baseline (1088.894 us; speedup 1.0000x reference)
//
#include <hip/hip_runtime.h>
#include <hip/hip_bf16.h>

// LSTM2: B=1024, T=1024, H=64. R10: R9 chain, trimmed.
// 256 blocks (4 batches) x 4 waves, 1 barrier/step, double-buffered h.
// vs R9: (1) transposed per-wave scratch scrT[(batch*16+unit)*4+gate] ->
// Phase A reads are 2x ds_read_b128 (was 8x scattered b32, 144 conflict
// cyc/step); writes stay 4x b128 per scr (gate-major f32x4 = register
// renaming of the 4 accumulators). (2) a2 = two 2-deep MFMA chains + add
// (was depth 4). (3) head finalize after MFMA issue (hides in MFMA shadow).
// Layouts (m89/m91/m120): A[m=lane&15][k=(lane>>4)*8+j],
// B[k=(lane>>4)*8+j][n=lane&15], C/D: row=(lane>>4)*4+reg, col=lane&15.

typedef _Float16 f16x8 __attribute__((ext_vector_type(8)));
typedef float    f32x4 __attribute__((ext_vector_type(4)));

namespace {
constexpr int Bb = 1024;
constexpr int Tt = 1024;
constexpr int NBat = 4;    // batches per block
constexpr int HSTR = 72;   // f16 stride per batch row of h
constexpr int XSTR = 1025; // f32 stride per batch row of x

__device__ __forceinline__ float sigm(float x) {
    float e = __builtin_amdgcn_exp2f(-1.4426950408889634f * x);
    return __builtin_amdgcn_rcpf(1.0f + e);
}
__device__ __forceinline__ float tanh_f(float x) {
    float e = __builtin_amdgcn_exp2f(-2.8853900817779268f * x);
    return __builtin_amdgcn_rcpf(1.0f + e) * 2.0f - 1.0f;
}
// Dtype sniff (proven R2-R9).
__device__ __forceinline__ bool detect_f32(const void* w) {
    const unsigned short* p = (const unsigned short*)w;
    int sane = 0;
    for (int i = 0; i < 64; ++i) {
        int e = (p[2 * i] >> 7) & 0xFF;
        if (e >= 107 && e <= 129) ++sane;
    }
    return sane < 32;
}
__device__ __forceinline__ float ld(const void* p, int i, bool f32) {
    return f32 ? ((const float*)p)[i]
               : __bfloat162float(((const __hip_bfloat16*)p)[i]);
}
__device__ __forceinline__ void st(void* p, int i, float v, bool f32) {
    if (f32) ((float*)p)[i] = v;
    else     ((__hip_bfloat16*)p)[i] = __float2bfloat16(v);
}
} // namespace

__global__ __launch_bounds__(256, 1) void lstm2_kernel(
    const void* __restrict__ x,      // [B, T]
    const void* __restrict__ w_ih1,  // [256, 1]
    const void* __restrict__ w_hh1,  // [256, 64]
    const void* __restrict__ b_ih1,  // [256]
    const void* __restrict__ b_hh1,  // [256]
    const void* __restrict__ w_ih2,  // [256, 64]
    const void* __restrict__ w_hh2,  // [256, 64]
    const void* __restrict__ b_ih2,  // [256]
    const void* __restrict__ b_hh2,  // [256]
    const void* __restrict__ w_lin,  // [1, 64]
    const void* __restrict__ b_lin,  // [1]
    void* __restrict__ out)          // [B, T]
{
    const int tid  = threadIdx.x;
    const int lane = tid & 63;
    const int w    = tid >> 6;       // wave -> unit group 16w..16w+15
    const int m    = lane & 15;      // MFMA col (batch; valid m<NBat)
    const int quad = lane >> 4;
    const int bb   = blockIdx.x * NBat;

    const bool f32 = detect_f32(w_hh1);

    __shared__ float                  xs[NBat * XSTR];
    __shared__ __align__(16) _Float16 h1buf[2][16 * HSTR];  // double-buffered
    __shared__ __align__(16) _Float16 h2buf[2][16 * HSTR];
    // transposed scratch: [wave][(batch*16 + unit_loc)*4 + gate]
    __shared__ __align__(16) float    scrT1[4][NBat * 16 * 4];
    __shared__ __align__(16) float    scrT2[4][NBat * 16 * 4];
    __shared__ float                  headl[2][16];         // [buf][w*4+b]

    // ---- stage x + zero h buffers (rows >= NBat stay 0 forever) ----
    for (int i = tid; i < NBat * 1024; i += 256)
        xs[(i >> 10) * XSTR + (i & 1023)] = ld(x, (bb + (i >> 10)) * Tt + (i & 1023), f32);
    for (int i = tid; i < 16 * HSTR; i += 256) {
        h1buf[0][i] = (_Float16)0; h1buf[1][i] = (_Float16)0;
        h2buf[0][i] = (_Float16)0; h2buf[1][i] = (_Float16)0;
    }

    // ---- one-time: A-fragments (96 VGPRs): elem j = W[64q+16w+m][32s+quad*8+j]
    f16x8 wf1[4][2], wf2[4][2], wf3[4][2];
    if (f32) {
        const float* W1 = (const float*)w_hh1;
        const float* W2 = (const float*)w_ih2;
        const float* W3 = (const float*)w_hh2;
#pragma unroll
        for (int q = 0; q < 4; ++q) {
            const int row = 64 * q + 16 * w + m;
#pragma unroll
            for (int s = 0; s < 2; ++s) {
                const int base = row * 64 + 32 * s + quad * 8;
#pragma unroll
                for (int j = 0; j < 8; ++j) {
                    wf1[q][s][j] = (_Float16)W1[base + j];
                    wf2[q][s][j] = (_Float16)W2[base + j];
                    wf3[q][s][j] = (_Float16)W3[base + j];
                }
            }
        }
    } else {
        const __hip_bfloat16* W1 = (const __hip_bfloat16*)w_hh1;
        const __hip_bfloat16* W2 = (const __hip_bfloat16*)w_ih2;
        const __hip_bfloat16* W3 = (const __hip_bfloat16*)w_hh2;
#pragma unroll
        for (int q = 0; q < 4; ++q) {
            const int row = 64 * q + 16 * w + m;
#pragma unroll
            for (int s = 0; s < 2; ++s) {
                const int base = row * 64 + 32 * s + quad * 8;
#pragma unroll
                for (int j = 0; j < 8; ++j) {
                    wf1[q][s][j] = (_Float16)__bfloat162float(W1[base + j]);
                    wf2[q][s][j] = (_Float16)__bfloat162float(W2[base + j]);
                    wf3[q][s][j] = (_Float16)__bfloat162float(W3[base + j]);
                }
            }
        }
    }
    f32x4 b1v[4], b2v[4], wxv[4];
#pragma unroll
    for (int q = 0; q < 4; ++q)
#pragma unroll
        for (int r = 0; r < 4; ++r) {
            const int row = 64 * q + 16 * w + quad * 4 + r;
            b1v[q][r] = ld(b_ih1, row, f32) + ld(b_hh1, row, f32);
            b2v[q][r] = ld(b_ih2, row, f32) + ld(b_hh2, row, f32);
            wxv[q][r] = ld(w_ih1, row, f32);
        }
    // cell mapping: lane -> (batch cb, unit 16w+uo)
    const int cb = lane >> 4;
    const int uo = lane & 15;
    const int cidx = (cb * 16 + uo) * 4;   // f32x4-aligned gate quad
    const float wl_u = ld(w_lin, 16 * w + uo, f32);
    const float blin = ld(b_lin, 0, f32);
    float c1 = 0.0f, c2 = 0.0f;
    __syncthreads();   // xs + zeroed h bufs visible

    // ---- prologue: pre1(0) = x_0*wx + b1 -> scrT1 (gate-major) ----
    if (m < NBat) {
        const float x0 = xs[m * XSTR];
#pragma unroll
        for (int r = 0; r < 4; ++r) {
            f32x4 v;
#pragma unroll
            for (int q = 0; q < 4; ++q) v[q] = fmaf(x0, wxv[q][r], b1v[q][r]);
            *(f32x4*)&scrT1[w][(m * 16 + quad * 4 + r) * 4] = v;
        }
    }
    // no barrier: A(0) reads own-wave scratch only (in-order DS)

    for (int t = 0; t < Tt; ++t) {
        const int cur = t & 1;
        // ---- Phase A: cells (own-wave transposed scratch; 1 eval/lane/layer)
        {
            const f32x4 g = *(const f32x4*)&scrT1[w][cidx];   // i,f,g,o
            float ig = sigm(g[0]), fg = sigm(g[1]);
            float gg = tanh_f(g[2]), og = sigm(g[3]);
            c1 = fmaf(fg, c1, ig * gg);
            h1buf[cur][cb * HSTR + 16 * w + uo] = (_Float16)(og * tanh_f(c1));
        }
        if (t > 0) {
            const f32x4 g = *(const f32x4*)&scrT2[w][cidx];
            float ig = sigm(g[0]), fg = sigm(g[1]);
            float gg = tanh_f(g[2]), og = sigm(g[3]);
            c2 = fmaf(fg, c2, ig * gg);
            float h = og * tanh_f(c2);
            h2buf[cur][cb * HSTR + 16 * w + uo] = (_Float16)h;
            float p = h * wl_u;               // partial over this wave's units
            p += __shfl_xor(p, 1); p += __shfl_xor(p, 2);
            p += __shfl_xor(p, 4); p += __shfl_xor(p, 8);
            if (uo == 0) headl[cur][w * 4 + cb] = p;
        }
        __syncthreads();                      // THE barrier: h_t / partials

        // ---- Phase B: MFMA (head finalize hidden in MFMA shadow) ----
        const f16x8 bh1a = *(const f16x8*)(h1buf[cur] + m * HSTR + quad * 8);
        const f16x8 bh1b = *(const f16x8*)(h1buf[cur] + m * HSTR + 32 + quad * 8);
        const f16x8 bh2a = *(const f16x8*)(h2buf[cur] + m * HSTR + quad * 8);
        const f16x8 bh2b = *(const f16x8*)(h2buf[cur] + m * HSTR + 32 + quad * 8);
        const float xtn  = xs[(m & (NBat - 1)) * XSTR + ((t + 1 < Tt) ? t + 1 : t)];
        f32x4 a1[4], a2[4];
#pragma unroll
        for (int q = 0; q < 4; ++q) {
            // two independent 2-deep chains, then add
            f32x4 p2 = __builtin_amdgcn_mfma_f32_16x16x32_f16(wf2[q][0], bh1a, b2v[q], 0, 0, 0);
            p2 = __builtin_amdgcn_mfma_f32_16x16x32_f16(wf2[q][1], bh1b, p2, 0, 0, 0);
            f32x4 p3 = __builtin_amdgcn_mfma_f32_16x16x32_f16(wf3[q][0], bh2a, f32x4{0,0,0,0}, 0, 0, 0);
            p3 = __builtin_amdgcn_mfma_f32_16x16x32_f16(wf3[q][1], bh2b, p3, 0, 0, 0);
            f32x4 i1;
#pragma unroll
            for (int r = 0; r < 4; ++r) i1[r] = fmaf(xtn, wxv[q][r], b1v[q][r]);
            i1 = __builtin_amdgcn_mfma_f32_16x16x32_f16(wf1[q][0], bh1a, i1, 0, 0, 0);
            a1[q] = __builtin_amdgcn_mfma_f32_16x16x32_f16(wf1[q][1], bh1b, i1, 0, 0, 0);
            a2[q] = p2 + p3;
        }
        if (t > 0 && tid < NBat) {            // wave 0: finalize out[t-1]
            float s = blin;
#pragma unroll
            for (int k = 0; k < 4; ++k) s += headl[cur][k * 4 + tid];
            st(out, (bb + tid) * Tt + (t - 1), s, f32);
        }
        if (m < NBat) {                       // gate-major stores (reg renaming)
#pragma unroll
            for (int r = 0; r < 4; ++r) {
                const int idx = (m * 16 + quad * 4 + r) * 4;
                *(f32x4*)&scrT2[w][idx] = f32x4{a2[0][r], a2[1][r], a2[2][r], a2[3][r]};
                *(f32x4*)&scrT1[w][idx] = f32x4{a1[0][r], a1[1][r], a1[2][r], a1[3][r]};
            }
        }
        // no second barrier: h double-buffered; scratch per-wave in-order
    }

    // ---- epilogue: cell2(T-1) + head + out[T-1] ----
    {
        const f32x4 g = *(const f32x4*)&scrT2[w][cidx];
        float ig = sigm(g[0]), fg = sigm(g[1]);
        float gg = tanh_f(g[2]), og = sigm(g[3]);
        c2 = fmaf(fg, c2, ig * gg);
        float h = og * tanh_f(c2);
        float p = h * wl_u;
        p += __shfl_xor(p, 1); p += __shfl_xor(p, 2);
        p += __shfl_xor(p, 4); p += __shfl_xor(p, 8);
        if (uo == 0) headl[0][w * 4 + cb] = p;
    }
    __syncthreads();
    if (tid < NBat) {
        float s = blin;
#pragma unroll
        for (int k = 0; k < 4; ++k) s += headl[0][k * 4 + tid];
        st(out, (bb + tid) * Tt + (Tt - 1), s, f32);
    }
}

extern "C" void kernel_launch(void* const* d_in, const int* in_sizes, int n_in,
                              void* d_out, int out_size, void* d_ws, size_t ws_size,
                              hipStream_t stream)
{
    (void)in_sizes; (void)n_in; (void)out_size; (void)d_ws; (void)ws_size;
    lstm2_kernel<<<dim3(Bb / NBat), dim3(256), 0, stream>>>(
        d_in[0], d_in[1], d_in[2], d_in[3], d_in[4], d_in[5],
        d_in[6], d_in[7], d_in[8], d_in[9], d_in[10], d_out);
}

// Round 11
// 1040.359 us; speedup vs baseline: 1.0467x; 1.0467x over previous
//
#include <hip/hip_runtime.h>
#include <hip/hip_bf16.h>

// LSTM2: B=1024, T=1024, H=64. R11: R10 transposed scratch + XOR bank swizzle.
// 256 blocks (4 batches) x 4 waves, 1 barrier/step, double-buffered h.
// R10 post-mortem: gate-major scratch WRITES were 8-way bank-conflicted
// (16 writers vary in row bits 2-5, bank group = row bits 0-2) -> +320
// conflict-cyc/step on the serial chain. Fix: storedRow = row ^ ((row>>3)&7):
//   writes: bank group = (row%8) ^ (m*2 + (quad>>1)) -> every group hit
//           exactly 2x across the 16 writers -> 2-way = free (m136).
//   reads:  lane -> chunk lane^((lane>>3)&7); any 8 consecutive lanes form an
//           XOR-const permutation of residues mod 8 -> conflict-free.
// Layouts (m89/m91/m120): A[m=lane&15][k=(lane>>4)*8+j],
// B[k=(lane>>4)*8+j][n=lane&15], C/D: row=(lane>>4)*4+reg, col=lane&15.

typedef _Float16 f16x8 __attribute__((ext_vector_type(8)));
typedef float    f32x4 __attribute__((ext_vector_type(4)));

namespace {
constexpr int Bb = 1024;
constexpr int Tt = 1024;
constexpr int NBat = 4;    // batches per block
constexpr int HSTR = 72;   // f16 stride per batch row of h
constexpr int XSTR = 1025; // f32 stride per batch row of x

__device__ __forceinline__ int srow(int row) {      // bank-swizzled row
    return row ^ ((row >> 3) & 7);
}
__device__ __forceinline__ float sigm(float x) {
    float e = __builtin_amdgcn_exp2f(-1.4426950408889634f * x);
    return __builtin_amdgcn_rcpf(1.0f + e);
}
__device__ __forceinline__ float tanh_f(float x) {
    float e = __builtin_amdgcn_exp2f(-2.8853900817779268f * x);
    return __builtin_amdgcn_rcpf(1.0f + e) * 2.0f - 1.0f;
}
// Dtype sniff (proven R2-R10).
__device__ __forceinline__ bool detect_f32(const void* w) {
    const unsigned short* p = (const unsigned short*)w;
    int sane = 0;
    for (int i = 0; i < 64; ++i) {
        int e = (p[2 * i] >> 7) & 0xFF;
        if (e >= 107 && e <= 129) ++sane;
    }
    return sane < 32;
}
__device__ __forceinline__ float ld(const void* p, int i, bool f32) {
    return f32 ? ((const float*)p)[i]
               : __bfloat162float(((const __hip_bfloat16*)p)[i]);
}
__device__ __forceinline__ void st(void* p, int i, float v, bool f32) {
    if (f32) ((float*)p)[i] = v;
    else     ((__hip_bfloat16*)p)[i] = __float2bfloat16(v);
}
} // namespace

__global__ __launch_bounds__(256, 1) void lstm2_kernel(
    const void* __restrict__ x,      // [B, T]
    const void* __restrict__ w_ih1,  // [256, 1]
    const void* __restrict__ w_hh1,  // [256, 64]
    const void* __restrict__ b_ih1,  // [256]
    const void* __restrict__ b_hh1,  // [256]
    const void* __restrict__ w_ih2,  // [256, 64]
    const void* __restrict__ w_hh2,  // [256, 64]
    const void* __restrict__ b_ih2,  // [256]
    const void* __restrict__ b_hh2,  // [256]
    const void* __restrict__ w_lin,  // [1, 64]
    const void* __restrict__ b_lin,  // [1]
    void* __restrict__ out)          // [B, T]
{
    const int tid  = threadIdx.x;
    const int lane = tid & 63;
    const int w    = tid >> 6;       // wave -> unit group 16w..16w+15
    const int m    = lane & 15;      // MFMA col (batch; valid m<NBat)
    const int quad = lane >> 4;
    const int bb   = blockIdx.x * NBat;

    const bool f32 = detect_f32(w_hh1);

    __shared__ float                  xs[NBat * XSTR];
    __shared__ __align__(16) _Float16 h1buf[2][16 * HSTR];  // double-buffered
    __shared__ __align__(16) _Float16 h2buf[2][16 * HSTR];
    // transposed scratch: [wave][srow(batch*16+unit)*4 + gate]
    __shared__ __align__(16) float    scrT1[4][NBat * 16 * 4];
    __shared__ __align__(16) float    scrT2[4][NBat * 16 * 4];
    __shared__ float                  headl[2][16];         // [buf][w*4+b]

    // ---- stage x + zero h buffers (rows >= NBat stay 0 forever) ----
    for (int i = tid; i < NBat * 1024; i += 256)
        xs[(i >> 10) * XSTR + (i & 1023)] = ld(x, (bb + (i >> 10)) * Tt + (i & 1023), f32);
    for (int i = tid; i < 16 * HSTR; i += 256) {
        h1buf[0][i] = (_Float16)0; h1buf[1][i] = (_Float16)0;
        h2buf[0][i] = (_Float16)0; h2buf[1][i] = (_Float16)0;
    }

    // ---- one-time: A-fragments (96 VGPRs): elem j = W[64q+16w+m][32s+quad*8+j]
    f16x8 wf1[4][2], wf2[4][2], wf3[4][2];
    if (f32) {
        const float* W1 = (const float*)w_hh1;
        const float* W2 = (const float*)w_ih2;
        const float* W3 = (const float*)w_hh2;
#pragma unroll
        for (int q = 0; q < 4; ++q) {
            const int row = 64 * q + 16 * w + m;
#pragma unroll
            for (int s = 0; s < 2; ++s) {
                const int base = row * 64 + 32 * s + quad * 8;
#pragma unroll
                for (int j = 0; j < 8; ++j) {
                    wf1[q][s][j] = (_Float16)W1[base + j];
                    wf2[q][s][j] = (_Float16)W2[base + j];
                    wf3[q][s][j] = (_Float16)W3[base + j];
                }
            }
        }
    } else {
        const __hip_bfloat16* W1 = (const __hip_bfloat16*)w_hh1;
        const __hip_bfloat16* W2 = (const __hip_bfloat16*)w_ih2;
        const __hip_bfloat16* W3 = (const __hip_bfloat16*)w_hh2;
#pragma unroll
        for (int q = 0; q < 4; ++q) {
            const int row = 64 * q + 16 * w + m;
#pragma unroll
            for (int s = 0; s < 2; ++s) {
                const int base = row * 64 + 32 * s + quad * 8;
#pragma unroll
                for (int j = 0; j < 8; ++j) {
                    wf1[q][s][j] = (_Float16)__bfloat162float(W1[base + j]);
                    wf2[q][s][j] = (_Float16)__bfloat162float(W2[base + j]);
                    wf3[q][s][j] = (_Float16)__bfloat162float(W3[base + j]);
                }
            }
        }
    }
    f32x4 b1v[4], b2v[4], wxv[4];
#pragma unroll
    for (int q = 0; q < 4; ++q)
#pragma unroll
        for (int r = 0; r < 4; ++r) {
            const int row = 64 * q + 16 * w + quad * 4 + r;
            b1v[q][r] = ld(b_ih1, row, f32) + ld(b_hh1, row, f32);
            b2v[q][r] = ld(b_ih2, row, f32) + ld(b_hh2, row, f32);
            wxv[q][r] = ld(w_ih1, row, f32);
        }
    // cell mapping: lane -> (batch cb, unit 16w+uo); swizzled gate-quad index
    const int cb = lane >> 4;
    const int uo = lane & 15;
    const int cidx = srow(lane) * 4;      // srow(cb*16+uo) * 4, 16B-aligned
    const float wl_u = ld(w_lin, 16 * w + uo, f32);
    const float blin = ld(b_lin, 0, f32);
    float c1 = 0.0f, c2 = 0.0f;
    __syncthreads();   // xs + zeroed h bufs visible

    // ---- prologue: pre1(0) = x_0*wx + b1 -> scrT1 (gate-major, swizzled) ----
    if (m < NBat) {
        const float x0 = xs[m * XSTR];
#pragma unroll
        for (int r = 0; r < 4; ++r) {
            f32x4 v;
#pragma unroll
            for (int q = 0; q < 4; ++q) v[q] = fmaf(x0, wxv[q][r], b1v[q][r]);
            *(f32x4*)&scrT1[w][srow(m * 16 + quad * 4 + r) * 4] = v;
        }
    }
    // no barrier: A(0) reads own-wave scratch only (in-order DS)

    for (int t = 0; t < Tt; ++t) {
        const int cur = t & 1;
        // ---- Phase A: cells (own-wave swizzled scratch; 1 eval/lane/layer)
        {
            const f32x4 g = *(const f32x4*)&scrT1[w][cidx];   // i,f,g,o
            float ig = sigm(g[0]), fg = sigm(g[1]);
            float gg = tanh_f(g[2]), og = sigm(g[3]);
            c1 = fmaf(fg, c1, ig * gg);
            h1buf[cur][cb * HSTR + 16 * w + uo] = (_Float16)(og * tanh_f(c1));
        }
        if (t > 0) {
            const f32x4 g = *(const f32x4*)&scrT2[w][cidx];
            float ig = sigm(g[0]), fg = sigm(g[1]);
            float gg = tanh_f(g[2]), og = sigm(g[3]);
            c2 = fmaf(fg, c2, ig * gg);
            float h = og * tanh_f(c2);
            h2buf[cur][cb * HSTR + 16 * w + uo] = (_Float16)h;
            float p = h * wl_u;               // partial over this wave's units
            p += __shfl_xor(p, 1); p += __shfl_xor(p, 2);
            p += __shfl_xor(p, 4); p += __shfl_xor(p, 8);
            if (uo == 0) headl[cur][w * 4 + cb] = p;
        }
        __syncthreads();                      // THE barrier: h_t / partials

        // ---- Phase B: MFMA (head finalize hidden in MFMA shadow) ----
        const f16x8 bh1a = *(const f16x8*)(h1buf[cur] + m * HSTR + quad * 8);
        const f16x8 bh1b = *(const f16x8*)(h1buf[cur] + m * HSTR + 32 + quad * 8);
        const f16x8 bh2a = *(const f16x8*)(h2buf[cur] + m * HSTR + quad * 8);
        const f16x8 bh2b = *(const f16x8*)(h2buf[cur] + m * HSTR + 32 + quad * 8);
        const float xtn  = xs[(m & (NBat - 1)) * XSTR + ((t + 1 < Tt) ? t + 1 : t)];
        f32x4 a1[4], a2[4];
#pragma unroll
        for (int q = 0; q < 4; ++q) {
            // two independent 2-deep chains, then add
            f32x4 p2 = __builtin_amdgcn_mfma_f32_16x16x32_f16(wf2[q][0], bh1a, b2v[q], 0, 0, 0);
            p2 = __builtin_amdgcn_mfma_f32_16x16x32_f16(wf2[q][1], bh1b, p2, 0, 0, 0);
            f32x4 p3 = __builtin_amdgcn_mfma_f32_16x16x32_f16(wf3[q][0], bh2a, f32x4{0,0,0,0}, 0, 0, 0);
            p3 = __builtin_amdgcn_mfma_f32_16x16x32_f16(wf3[q][1], bh2b, p3, 0, 0, 0);
            f32x4 i1;
#pragma unroll
            for (int r = 0; r < 4; ++r) i1[r] = fmaf(xtn, wxv[q][r], b1v[q][r]);
            i1 = __builtin_amdgcn_mfma_f32_16x16x32_f16(wf1[q][0], bh1a, i1, 0, 0, 0);
            a1[q] = __builtin_amdgcn_mfma_f32_16x16x32_f16(wf1[q][1], bh1b, i1, 0, 0, 0);
            a2[q] = p2 + p3;
        }
        if (t > 0 && tid < NBat) {            // wave 0: finalize out[t-1]
            float s = blin;
#pragma unroll
            for (int k = 0; k < 4; ++k) s += headl[cur][k * 4 + tid];
            st(out, (bb + tid) * Tt + (t - 1), s, f32);
        }
        if (m < NBat) {                       // gate-major swizzled stores
#pragma unroll
            for (int r = 0; r < 4; ++r) {
                const int idx = srow(m * 16 + quad * 4 + r) * 4;
                *(f32x4*)&scrT2[w][idx] = f32x4{a2[0][r], a2[1][r], a2[2][r], a2[3][r]};
                *(f32x4*)&scrT1[w][idx] = f32x4{a1[0][r], a1[1][r], a1[2][r], a1[3][r]};
            }
        }
        // no second barrier: h double-buffered; scratch per-wave in-order
    }

    // ---- epilogue: cell2(T-1) + head + out[T-1] ----
    {
        const f32x4 g = *(const f32x4*)&scrT2[w][cidx];
        float ig = sigm(g[0]), fg = sigm(g[1]);
        float gg = tanh_f(g[2]), og = sigm(g[3]);
        c2 = fmaf(fg, c2, ig * gg);
        float h = og * tanh_f(c2);
        float p = h * wl_u;
        p += __shfl_xor(p, 1); p += __shfl_xor(p, 2);
        p += __shfl_xor(p, 4); p += __shfl_xor(p, 8);
        if (uo == 0) headl[0][w * 4 + cb] = p;
    }
    __syncthreads();
    if (tid < NBat) {
        float s = blin;
#pragma unroll
        for (int k = 0; k < 4; ++k) s += headl[0][k * 4 + tid];
        st(out, (bb + tid) * Tt + (Tt - 1), s, f32);
    }
}

extern "C" void kernel_launch(void* const* d_in, const int* in_sizes, int n_in,
                              void* d_out, int out_size, void* d_ws, size_t ws_size,
                              hipStream_t stream)
{
    (void)in_sizes; (void)n_in; (void)out_size; (void)d_ws; (void)ws_size;
    lstm2_kernel<<<dim3(Bb / NBat), dim3(256), 0, stream>>>(
        d_in[0], d_in[1], d_in[2], d_in[3], d_in[4], d_in[5],
        d_in[6], d_in[7], d_in[8], d_in[9], d_in[10], d_out);
}